// Round 1
// baseline (683.650 us; speedup 1.0000x reference)
//
#include <hip/hip_runtime.h>
#include <hip/hip_bf16.h>
#include <stdint.h>

#define SQ 2048     // sequence length
#define DK 64       // head dim
#define NB 32       // batch
#define TQ 16       // q rows per block
#define SCW 2052    // padded LDS score row width (f32 elems), keeps b128 align
#define NTHREADS 512

typedef __attribute__((ext_vector_type(8))) short short8;
typedef __attribute__((ext_vector_type(4))) float f32x4;

// ---- bf16 helpers (RNE) ----
__device__ __forceinline__ unsigned f2bf_u(float x) {
    unsigned u = __builtin_bit_cast(unsigned, x);
    u += 0x7fffu + ((u >> 16) & 1u);
    return u >> 16;                       // bf16 bits in low 16
}
__device__ __forceinline__ float bf2f(unsigned h) {
    return __builtin_bit_cast(float, h << 16);
}
// split 8 consecutive f32 into hi/lo bf16 fragments
__device__ __forceinline__ void split8(const float* p, short8& h, short8& l) {
    f32x4 a = *(const f32x4*)p;
    f32x4 b = *(const f32x4*)(p + 4);
    #pragma unroll
    for (int j = 0; j < 4; ++j) {
        unsigned ua = f2bf_u(a[j]);
        h[j] = (short)ua; l[j] = (short)f2bf_u(a[j] - bf2f(ua));
        unsigned ub = f2bf_u(b[j]);
        h[j + 4] = (short)ub; l[j + 4] = (short)f2bf_u(b[j] - bf2f(ub));
    }
}
// pack value as (bf16 hi << 16) | bf16 lo-residual
__device__ __forceinline__ unsigned packsplit(float x) {
    unsigned h = f2bf_u(x);
    unsigned l = f2bf_u(x - bf2f(h));
    return (h << 16) | l;
}

__global__ __launch_bounds__(NTHREADS) void sdpa_fused_kernel(
    const float* __restrict__ Q, const float* __restrict__ K,
    const float* __restrict__ V, const unsigned* __restrict__ Mk,
    float* __restrict__ Yout, float* __restrict__ Aout)
{
    __shared__ float sc[TQ * SCW];          // 128.25 KiB: scores -> exp -> packed attn
    __shared__ float yp[8][TQ][32];         // 16 KiB: PV partials
    __shared__ float i2s[TQ];               // 2/rowsum

    const int tid  = threadIdx.x;
    const int lane = tid & 63;
    const int wv   = tid >> 6;              // wave 0..7
    const int m16  = lane & 15;
    const int kq   = lane >> 4;             // 0..3
    const int koff = kq * 8;

    const int bidx = blockIdx.x;
    const int b    = bidx >> 7;             // 128 q-tiles per batch
    const int q0   = (bidx & 127) * TQ;

    // ================= Phase A: raw scores = Q K^T (unscaled) =================
    // A-frag: lane holds Q[q0 + (lane&15)][8*(lane>>4)+j + 32c]
    short8 qh[2], ql[2];
    {
        const float* qrow = Q + ((size_t)b * SQ + q0 + m16) * DK;
        split8(qrow + koff,      qh[0], ql[0]);
        split8(qrow + 32 + koff, qh[1], ql[1]);
    }
    for (int t = 0; t < 16; ++t) {
        const int kb = wv * 256 + t * 16;   // this wave's k-tile base
        const float* krow = K + ((size_t)b * SQ + kb + m16) * DK;
        f32x4 acc = {0.f, 0.f, 0.f, 0.f};
        #pragma unroll
        for (int c = 0; c < 2; ++c) {
            short8 kh, kl;
            split8(krow + c * 32 + koff, kh, kl);
            acc = __builtin_amdgcn_mfma_f32_16x16x32_bf16(qh[c], kh, acc, 0, 0, 0);
            acc = __builtin_amdgcn_mfma_f32_16x16x32_bf16(qh[c], kl, acc, 0, 0, 0);
            acc = __builtin_amdgcn_mfma_f32_16x16x32_bf16(ql[c], kh, acc, 0, 0, 0);
        }
        // C/D layout: col = lane&15, row = (lane>>4)*4 + reg
        #pragma unroll
        for (int r = 0; r < 4; ++r)
            sc[(kq * 4 + r) * SCW + kb + m16] = acc[r];
    }
    __syncthreads();

    // ================= Phase B: softmax (max, exp in place, sum) =================
    {
        const int row = tid >> 5;           // 16 rows x 32 threads
        const int sub = tid & 31;
        float* rp = sc + row * SCW;
        float mx = -3.4e38f;
        #pragma unroll
        for (int i = 0; i < 16; ++i) {
            f32x4 v = *(const f32x4*)(rp + sub * 4 + i * 128);
            mx = fmaxf(mx, fmaxf(fmaxf(v[0], v[1]), fmaxf(v[2], v[3])));
        }
        #pragma unroll
        for (int off = 16; off >= 1; off >>= 1)
            mx = fmaxf(mx, __shfl_xor(mx, off));
        float sum = 0.f;
        #pragma unroll 4
        for (int i = 0; i < 16; ++i) {
            float* pp = rp + sub * 4 + i * 128;
            f32x4 v = *(const f32x4*)pp;
            f32x4 e;
            #pragma unroll
            for (int j = 0; j < 4; ++j) {
                e[j] = __expf((v[j] - mx) * 0.125f);   // scale = 1/sqrt(64)
                sum += e[j];
            }
            *(f32x4*)pp = e;
        }
        #pragma unroll
        for (int off = 16; off >= 1; off >>= 1)
            sum += __shfl_xor(sum, off);
        if (sub == 0) i2s[row] = 2.0f / sum;           // includes dropout keep-scale
    }
    __syncthreads();

    // ====== Phase C: normalize + dropout mask + write attn + repack LDS ======
    {
        const size_t mrow0 = ((size_t)b * SQ + q0) * SQ;
        #pragma unroll 4
        for (int r = 0; r < TQ; ++r) {
            const size_t g = mrow0 + (size_t)r * SQ + tid * 4;
            uint4 mk = *(const uint4*)(Mk + g);
            f32x4 p  = *(const f32x4*)(sc + r * SCW + tid * 4);
            const float i2 = i2s[r];
            f32x4 a;
            a[0] = mk.x ? p[0] * i2 : 0.f;
            a[1] = mk.y ? p[1] * i2 : 0.f;
            a[2] = mk.z ? p[2] * i2 : 0.f;
            a[3] = mk.w ? p[3] * i2 : 0.f;
            *(f32x4*)(Aout + g) = a;
            uint4 pk;
            pk.x = packsplit(a[0]);
            pk.y = packsplit(a[1]);
            pk.z = packsplit(a[2]);
            pk.w = packsplit(a[3]);
            // in-place: each thread rewrites exactly the 4 slots it read
            *(uint4*)((unsigned*)sc + r * SCW + tid * 4) = pk;
        }
    }
    __syncthreads();

    // ================= Phase D: y = attn * V (split-A bf16 MFMA) =================
    {
        f32x4 acc0 = {0.f, 0.f, 0.f, 0.f};
        f32x4 acc1 = {0.f, 0.f, 0.f, 0.f};
        const int kq4 = wv & 3;             // 4-way k split
        const int dh  = wv >> 2;            // 2-way d split
        for (int ch = 0; ch < 16; ++ch) {
            const int k0 = kq4 * 512 + ch * 32;
            const unsigned* ar = (const unsigned*)sc + m16 * SCW + k0 + koff;
            uint4 u0 = *(const uint4*)ar;
            uint4 u1 = *(const uint4*)(ar + 4);
            short8 ah, al;
            ah[0]=(short)(u0.x>>16); al[0]=(short)(u0.x&0xffffu);
            ah[1]=(short)(u0.y>>16); al[1]=(short)(u0.y&0xffffu);
            ah[2]=(short)(u0.z>>16); al[2]=(short)(u0.z&0xffffu);
            ah[3]=(short)(u0.w>>16); al[3]=(short)(u0.w&0xffffu);
            ah[4]=(short)(u1.x>>16); al[4]=(short)(u1.x&0xffffu);
            ah[5]=(short)(u1.y>>16); al[5]=(short)(u1.y&0xffffu);
            ah[6]=(short)(u1.z>>16); al[6]=(short)(u1.z&0xffffu);
            ah[7]=(short)(u1.w>>16); al[7]=(short)(u1.w&0xffffu);
            const float* vbase = V + ((size_t)b * SQ + k0 + koff) * DK;
            #pragma unroll
            for (int dd = 0; dd < 2; ++dd) {
                const int dcol = (dh * 2 + dd) * 16 + m16;
                short8 vb;
                #pragma unroll
                for (int j = 0; j < 8; ++j)
                    vb[j] = (short)f2bf_u(vbase[(size_t)j * DK + dcol]);
                if (dd == 0) {
                    acc0 = __builtin_amdgcn_mfma_f32_16x16x32_bf16(ah, vb, acc0, 0, 0, 0);
                    acc0 = __builtin_amdgcn_mfma_f32_16x16x32_bf16(al, vb, acc0, 0, 0, 0);
                } else {
                    acc1 = __builtin_amdgcn_mfma_f32_16x16x32_bf16(ah, vb, acc1, 0, 0, 0);
                    acc1 = __builtin_amdgcn_mfma_f32_16x16x32_bf16(al, vb, acc1, 0, 0, 0);
                }
            }
        }
        #pragma unroll
        for (int r = 0; r < 4; ++r) {
            yp[wv][kq * 4 + r][m16]      = acc0[r];
            yp[wv][kq * 4 + r][16 + m16] = acc1[r];
        }
    }
    __syncthreads();

    // ================= reduce partials, write y =================
    {
        const int q  = tid >> 5;            // 0..15
        const int d0 = (tid & 31) * 2;      // 0..62 (even)
        const int wb = (d0 >> 5) * 4;       // wave group holding this d half
        const int c0 = d0 & 31;
        float s0 = 0.f, s1 = 0.f;
        #pragma unroll
        for (int j = 0; j < 4; ++j) {
            s0 += yp[wb + j][q][c0];
            s1 += yp[wb + j][q][c0 + 1];
        }
        float* yo = Yout + ((size_t)b * SQ + q0 + q) * DK + d0;
        yo[0] = s0;
        yo[1] = s1;
    }
}

extern "C" void kernel_launch(void* const* d_in, const int* in_sizes, int n_in,
                              void* d_out, int out_size, void* d_ws, size_t ws_size,
                              hipStream_t stream) {
    const float*    Q  = (const float*)d_in[0];
    const float*    K  = (const float*)d_in[1];
    const float*    V  = (const float*)d_in[2];
    const unsigned* Mk = (const unsigned*)d_in[3];   // bool mask delivered as int32 0/1
    float* Yout = (float*)d_out;
    float* Aout = (float*)d_out + (size_t)NB * SQ * DK;   // tuple order: (y, attn)
    sdpa_fused_kernel<<<dim3(NB * (SQ / TQ)), dim3(NTHREADS), 0, stream>>>(
        Q, K, V, Mk, Yout, Aout);
}

// Round 2
// 507.576 us; speedup vs baseline: 1.3469x; 1.3469x over previous
//
#include <hip/hip_runtime.h>
#include <hip/hip_bf16.h>
#include <stdint.h>

#define SQ 2048
#define DK 64
#define NB 32
#define TQ 16
#define EW 2064            // fp16 elems per LDS score row (pad: 2048+16)
#define NTHREADS 512
#define SCL 0.18033688011112042f   // log2(e)/8  -> exp(s/8) == exp2(s*SCL)

typedef __attribute__((ext_vector_type(8))) short short8;
typedef __attribute__((ext_vector_type(4))) float f32x4;

// ---- bf16 helpers (RNE) ----
__device__ __forceinline__ unsigned f2bf_u(float x) {
    unsigned u = __builtin_bit_cast(unsigned, x);
    u += 0x7fffu + ((u >> 16) & 1u);
    return u >> 16;
}
__device__ __forceinline__ float bf2f(unsigned h) {
    return __builtin_bit_cast(float, h << 16);
}
__device__ __forceinline__ void split8(const float* p, short8& h, short8& l) {
    f32x4 a = *(const f32x4*)p;
    f32x4 b = *(const f32x4*)(p + 4);
    #pragma unroll
    for (int j = 0; j < 4; ++j) {
        unsigned ua = f2bf_u(a[j]);
        h[j] = (short)ua; l[j] = (short)f2bf_u(a[j] - bf2f(ua));
        unsigned ub = f2bf_u(b[j]);
        h[j + 4] = (short)ub; l[j + 4] = (short)f2bf_u(b[j] - bf2f(ub));
    }
}
__device__ __forceinline__ unsigned pkf16(float a, float b) {
    unsigned short ha = __builtin_bit_cast(unsigned short, (_Float16)a);
    unsigned short hb = __builtin_bit_cast(unsigned short, (_Float16)b);
    return (unsigned)ha | ((unsigned)hb << 16);
}
__device__ __forceinline__ float upk16(unsigned u, int hi) {
    return (float)__builtin_bit_cast(_Float16, (unsigned short)(hi ? (u >> 16) : (u & 0xffffu)));
}

// ============ prep: K -> bf16 hi/lo planes; V -> transposed bf16 plane ============
__global__ __launch_bounds__(256) void prep_kernel(
    const float* __restrict__ K, const float* __restrict__ V,
    unsigned short* __restrict__ Khi, unsigned short* __restrict__ Klo,
    unsigned short* __restrict__ Vt)
{
    __shared__ float vtile[64][65];
    const int t  = threadIdx.x;
    const int b  = blockIdx.x >> 5;
    const int s0 = (blockIdx.x & 31) << 6;
    const size_t base = ((size_t)b * SQ + s0) * DK + (size_t)t * 16;

    // K planes (16 elems/thread, coalesced 64B chunks)
    {
        short8 h0, l0, h1, l1;
        split8(K + base,     h0, l0);
        split8(K + base + 8, h1, l1);
        *(short8*)(Khi + base)     = h0;
        *(short8*)(Khi + base + 8) = h1;
        *(short8*)(Klo + base)     = l0;
        *(short8*)(Klo + base + 8) = l1;
    }
    // V -> LDS f32 tile [s][d]
    {
        const int sr = t >> 2, dc = (t & 3) << 4;
        #pragma unroll
        for (int u = 0; u < 16; u += 4) {
            f32x4 v = *(const f32x4*)(V + base + u);
            vtile[sr][dc + u + 0] = v[0];
            vtile[sr][dc + u + 1] = v[1];
            vtile[sr][dc + u + 2] = v[2];
            vtile[sr][dc + u + 3] = v[3];
        }
    }
    __syncthreads();
    // transpose-write Vt[b][d][s] bf16, coalesced along s
    #pragma unroll
    for (int rep = 0; rep < 16; ++rep) {
        const int idx = rep * 256 + t;
        const int d = idx >> 6, s = idx & 63;
        Vt[((size_t)b * DK + d) * SQ + s0 + s] = (unsigned short)f2bf_u(vtile[s][d]);
    }
}

// ============ main fused kernel ============
__global__ __launch_bounds__(NTHREADS, 4) void sdpa_main(
    const float* __restrict__ Q, const unsigned short* __restrict__ Khi,
    const unsigned short* __restrict__ Klo, const unsigned short* __restrict__ Vt,
    const unsigned* __restrict__ Mk, float* __restrict__ Yout, float* __restrict__ Aout)
{
    __shared__ __align__(16) unsigned short e_lds[TQ][EW];  // 66048 B
    __shared__ float yp[2][TQ][DK];                         // 8192 B
    __shared__ float rsum[8][TQ];                           // 512 B
    __shared__ float i2s[TQ];

    const int tid  = threadIdx.x;
    const int lane = tid & 63;
    const int wv   = tid >> 6;
    const int m16  = lane & 15;
    const int kq   = lane >> 4;
    const int koff = kq * 8;

    const int b  = blockIdx.x >> 7;
    const int q0 = (blockIdx.x & 127) * TQ;

    // Q fragments (used as MFMA B-operand), split bf16 (tiny: 16 rows/block)
    short8 qh[2], ql[2];
    {
        const float* qrow = Q + ((size_t)b * SQ + q0 + m16) * DK;
        split8(qrow + koff,      qh[0], ql[0]);
        split8(qrow + 32 + koff, qh[1], ql[1]);
    }

    // ---- Phase A: e = exp(QK^T/8), fp16 -> LDS; per-row sums in-register ----
    // mfma(Kfrag, Qfrag): lane(m16,kq) reg r holds score(q=q0+m16, k=kb+kq*4+r)
    float rs = 0.f;
    {
        const size_t krow = ((size_t)b * SQ + wv * 256 + m16) * DK;
        const unsigned short* khp = Khi + krow;
        const unsigned short* klp = Klo + krow;
        for (int t = 0; t < 16; ++t) {
            const int off = t * 16 * DK;
            f32x4 acc = {0.f, 0.f, 0.f, 0.f};
            #pragma unroll
            for (int c = 0; c < 2; ++c) {
                short8 kh = *(const short8*)(khp + off + c * 32 + koff);
                short8 kl = *(const short8*)(klp + off + c * 32 + koff);
                acc = __builtin_amdgcn_mfma_f32_16x16x32_bf16(kh, qh[c], acc, 0, 0, 0);
                acc = __builtin_amdgcn_mfma_f32_16x16x32_bf16(kh, ql[c], acc, 0, 0, 0);
                acc = __builtin_amdgcn_mfma_f32_16x16x32_bf16(kl, qh[c], acc, 0, 0, 0);
            }
            const float e0 = exp2f(acc[0] * SCL);
            const float e1 = exp2f(acc[1] * SCL);
            const float e2 = exp2f(acc[2] * SCL);
            const float e3 = exp2f(acc[3] * SCL);
            rs += (e0 + e1) + (e2 + e3);
            uint2 pk;
            pk.x = pkf16(e0, e1);
            pk.y = pkf16(e2, e3);
            *(uint2*)&e_lds[m16][wv * 256 + t * 16 + kq * 4] = pk;
        }
    }
    rs += __shfl_xor(rs, 16);
    rs += __shfl_xor(rs, 32);
    if (lane < 16) rsum[wv][lane] = rs;
    __syncthreads();

    // ---- Phase B: combine row sums ----
    if (tid < 16) {
        float s = 0.f;
        #pragma unroll
        for (int w = 0; w < 8; ++w) s += rsum[w][tid];
        i2s[tid] = 2.0f / s;       // includes dropout keep-scale 1/(1-0.5)
    }
    __syncthreads();

    // ---- Phase C: normalize + dropout + write attn f32 + repack LDS as bf16 ----
    {
        const size_t g0 = ((size_t)b * SQ + q0) * SQ + (size_t)tid * 4;
        #pragma unroll 2
        for (int r = 0; r < TQ; ++r) {
            const uint4 mk = *(const uint4*)(Mk + g0 + (size_t)r * SQ);
            const uint2 ev = *(const uint2*)&e_lds[r][tid * 4];
            const float i2 = i2s[r];
            const float a0 = mk.x ? upk16(ev.x, 0) * i2 : 0.f;
            const float a1 = mk.y ? upk16(ev.x, 1) * i2 : 0.f;
            const float a2 = mk.z ? upk16(ev.y, 0) * i2 : 0.f;
            const float a3 = mk.w ? upk16(ev.y, 1) * i2 : 0.f;
            f32x4 av = {a0, a1, a2, a3};
            *(f32x4*)(Aout + g0 + (size_t)r * SQ) = av;
            uint2 pb;
            pb.x = f2bf_u(a0) | (f2bf_u(a1) << 16);
            pb.y = f2bf_u(a2) | (f2bf_u(a3) << 16);
            *(uint2*)&e_lds[r][tid * 4] = pb;   // in-place, same slots -> race-free
        }
    }
    __syncthreads();

    // ---- Phase D: y = attn * V via mfma(attn_frag, Vt_frag) ----
    {
        const int khalf = wv & 1;
        const int d0 = (wv >> 1) * 16;
        const unsigned short* vrow = Vt + ((size_t)b * DK + d0 + m16) * SQ;
        f32x4 acc = {0.f, 0.f, 0.f, 0.f};
        for (int ch = 0; ch < 32; ++ch) {
            const int k0 = khalf * 1024 + ch * 32;
            short8 af = *(const short8*)&e_lds[m16][k0 + koff];
            short8 vf = *(const short8*)(vrow + k0 + koff);
            acc = __builtin_amdgcn_mfma_f32_16x16x32_bf16(af, vf, acc, 0, 0, 0);
        }
        // lane(m16,kq) reg r holds y[q=kq*4+r][d=d0+m16]
        #pragma unroll
        for (int r = 0; r < 4; ++r)
            yp[khalf][kq * 4 + r][d0 + m16] = acc[r];
    }
    __syncthreads();

    // ---- reduce 2 k-halves, write y ----
    {
        const int q  = tid >> 5;
        const int dd = (tid & 31) * 2;
        float2 yv;
        yv.x = yp[0][q][dd]     + yp[1][q][dd];
        yv.y = yp[0][q][dd + 1] + yp[1][q][dd + 1];
        *(float2*)(Yout + ((size_t)b * SQ + q0 + q) * DK + dd) = yv;
    }
}

extern "C" void kernel_launch(void* const* d_in, const int* in_sizes, int n_in,
                              void* d_out, int out_size, void* d_ws, size_t ws_size,
                              hipStream_t stream) {
    const float*    Q  = (const float*)d_in[0];
    const float*    K  = (const float*)d_in[1];
    const float*    V  = (const float*)d_in[2];
    const unsigned* Mk = (const unsigned*)d_in[3];
    float* Yout = (float*)d_out;
    float* Aout = (float*)d_out + (size_t)NB * SQ * DK;

    const size_t NEL = (size_t)NB * SQ * DK;
    unsigned short* Khi = (unsigned short*)d_ws;
    unsigned short* Klo = Khi + NEL;
    unsigned short* Vt  = Klo + NEL;

    prep_kernel<<<dim3(NB * (SQ / 64)), dim3(256), 0, stream>>>(K, V, Khi, Klo, Vt);
    sdpa_main<<<dim3(NB * (SQ / TQ)), dim3(NTHREADS), 0, stream>>>(
        Q, Khi, Klo, Vt, Mk, Yout, Aout);
}

// Round 4
// 498.646 us; speedup vs baseline: 1.3710x; 1.0179x over previous
//
#include <hip/hip_runtime.h>
#include <hip/hip_bf16.h>
#include <stdint.h>

#define SQ 2048
#define DK 64
#define NB 32
#define TQ 16
#define EW 2064            // fp16 elems per LDS score row
#define NTHREADS 512
#define SCL 0.18033688011112042f   // log2(e)/8

typedef __attribute__((ext_vector_type(8))) short short8;
typedef __attribute__((ext_vector_type(4))) float f32x4;
typedef __attribute__((ext_vector_type(4))) unsigned u32x4;
typedef __attribute__((ext_vector_type(2))) unsigned u32x2;

// ---- bf16 helpers (RNE) ----
__device__ __forceinline__ unsigned f2bf_u(float x) {
    unsigned u = __builtin_bit_cast(unsigned, x);
    u += 0x7fffu + ((u >> 16) & 1u);
    return u >> 16;
}
__device__ __forceinline__ float bf2f(unsigned h) {
    return __builtin_bit_cast(float, h << 16);
}
__device__ __forceinline__ void split8(const float* p, short8& h, short8& l) {
    f32x4 a = *(const f32x4*)p;
    f32x4 b = *(const f32x4*)(p + 4);
    #pragma unroll
    for (int j = 0; j < 4; ++j) {
        unsigned ua = f2bf_u(a[j]);
        h[j] = (short)ua; l[j] = (short)f2bf_u(a[j] - bf2f(ua));
        unsigned ub = f2bf_u(b[j]);
        h[j + 4] = (short)ub; l[j + 4] = (short)f2bf_u(b[j] - bf2f(ub));
    }
}
__device__ __forceinline__ unsigned pkf16(float a, float b) {
    unsigned short ha = __builtin_bit_cast(unsigned short, (_Float16)a);
    unsigned short hb = __builtin_bit_cast(unsigned short, (_Float16)b);
    return (unsigned)ha | ((unsigned)hb << 16);
}
__device__ __forceinline__ float upk16(unsigned u, int hi) {
    return (float)__builtin_bit_cast(_Float16, (unsigned short)(hi ? (u >> 16) : (u & 0xffffu)));
}

// ============ prep: K -> bf16 hi/lo planes; V -> transposed bf16 plane ============
__global__ __launch_bounds__(256) void prep_kernel(
    const float* __restrict__ K, const float* __restrict__ V,
    unsigned short* __restrict__ Khi, unsigned short* __restrict__ Klo,
    unsigned short* __restrict__ Vt)
{
    __shared__ float vtile[64][65];
    const int t  = threadIdx.x;
    const int b  = blockIdx.x >> 5;
    const int s0 = (blockIdx.x & 31) << 6;
    const size_t base = ((size_t)b * SQ + s0) * DK + (size_t)t * 16;

    {
        short8 h0, l0, h1, l1;
        split8(K + base,     h0, l0);
        split8(K + base + 8, h1, l1);
        *(short8*)(Khi + base)     = h0;
        *(short8*)(Khi + base + 8) = h1;
        *(short8*)(Klo + base)     = l0;
        *(short8*)(Klo + base + 8) = l1;
    }
    {
        const int sr = t >> 2, dc = (t & 3) << 4;
        #pragma unroll
        for (int u = 0; u < 16; u += 4) {
            f32x4 v = *(const f32x4*)(V + base + u);
            vtile[sr][dc + u + 0] = v[0];
            vtile[sr][dc + u + 1] = v[1];
            vtile[sr][dc + u + 2] = v[2];
            vtile[sr][dc + u + 3] = v[3];
        }
    }
    __syncthreads();
    #pragma unroll
    for (int rep = 0; rep < 16; ++rep) {
        const int idx = rep * 256 + t;
        const int d = idx >> 6, s = idx & 63;
        Vt[((size_t)b * DK + d) * SQ + s0 + s] = (unsigned short)f2bf_u(vtile[s][d]);
    }
}

// ============ main fused kernel ============
__global__ __launch_bounds__(NTHREADS, 4) void sdpa_main(
    const float* __restrict__ Q, const unsigned short* __restrict__ Khi,
    const unsigned short* __restrict__ Klo, const unsigned short* __restrict__ Vt,
    const unsigned* __restrict__ Mk, float* __restrict__ Yout, float* __restrict__ Aout)
{
    __shared__ __align__(16) unsigned short e_lds[TQ][EW];  // 66048 B
    __shared__ float yp[4][TQ][16];                         // 4 KB
    __shared__ float rsum[8][TQ];
    __shared__ float i2s[TQ];

    const int tid  = threadIdx.x;
    const int lane = tid & 63;
    const int wv   = tid >> 6;
    const int m16  = lane & 15;
    const int kq   = lane >> 4;
    const int koff = kq * 8;

    const int b  = blockIdx.x >> 7;
    const int q0 = (blockIdx.x & 127) * TQ;

    // Q fragments (B-operand), split bf16
    short8 qh[2], ql[2];
    {
        const float* qrow = Q + ((size_t)b * SQ + q0 + m16) * DK;
        split8(qrow + koff,      qh[0], ql[0]);
        split8(qrow + 32 + koff, qh[1], ql[1]);
    }

    // ---- Phase A: e = exp(QK^T/8) (fp16, swizzled LDS); row sums in-register ----
    float rs = 0.f;
    {
        const size_t krow = ((size_t)b * SQ + wv * 256 + m16) * DK;
        const unsigned short* khp = Khi + krow;
        const unsigned short* klp = Klo + krow;
        const int xw = (m16 & 7) << 3;
        for (int t = 0; t < 16; ++t) {
            const int off = t * 16 * DK;
            f32x4 acc = {0.f, 0.f, 0.f, 0.f};
            #pragma unroll
            for (int c = 0; c < 2; ++c) {
                short8 kh = *(const short8*)(khp + off + c * 32 + koff);
                short8 kl = *(const short8*)(klp + off + c * 32 + koff);
                acc = __builtin_amdgcn_mfma_f32_16x16x32_bf16(kh, qh[c], acc, 0, 0, 0);
                acc = __builtin_amdgcn_mfma_f32_16x16x32_bf16(kh, ql[c], acc, 0, 0, 0);
                acc = __builtin_amdgcn_mfma_f32_16x16x32_bf16(kl, qh[c], acc, 0, 0, 0);
            }
            const float e0 = exp2f(acc[0] * SCL);
            const float e1 = exp2f(acc[1] * SCL);
            const float e2 = exp2f(acc[2] * SCL);
            const float e3 = exp2f(acc[3] * SCL);
            rs += (e0 + e1) + (e2 + e3);
            u32x2 pk;
            pk[0] = pkf16(e0, e1);
            pk[1] = pkf16(e2, e3);
            *(u32x2*)&e_lds[m16][(wv * 256 + t * 16 + kq * 4) ^ xw] = pk;
        }
    }
    rs += __shfl_xor(rs, 16);
    rs += __shfl_xor(rs, 32);
    if (lane < 16) rsum[wv][lane] = rs;
    __syncthreads();
    if (tid < 16) {
        float s = 0.f;
        #pragma unroll
        for (int w = 0; w < 8; ++w) s += rsum[w][tid];
        i2s[tid] = 2.0f / s;       // includes dropout keep-scale
    }
    __syncthreads();

    // ---- merged CD phase: stream mask+attn while PV MFMAs run underneath ----
    const int cr = tid >> 5;            // C row (0..15)
    const int cc = (tid & 31) * 8;      // C col base within stripe
    const int xc = (cr & 7) << 3;
    const float i2 = i2s[cr];
    const size_t crow = ((size_t)b * SQ + q0 + cr) * SQ + cc;

    const int g   = wv >> 1;            // d-group 0..3
    const int par = wv & 1;             // k-parity
    const int xm  = (m16 & 7) << 3;
    const unsigned short* vrow = Vt + ((size_t)b * DK + g * 16 + m16) * SQ;
    f32x4 acc = {0.f, 0.f, 0.f, 0.f};

    #define C_FINISH(s, ma, mb)                                                   \
    {                                                                             \
        unsigned short* ep = &e_lds[cr][((s) * 256 + cc) ^ xc];                   \
        const u32x4 ev = *(const u32x4*)ep;                                       \
        const float a0 = (ma)[0] ? upk16(ev[0], 0) * i2 : 0.f;                    \
        const float a1 = (ma)[1] ? upk16(ev[0], 1) * i2 : 0.f;                    \
        const float a2 = (ma)[2] ? upk16(ev[1], 0) * i2 : 0.f;                    \
        const float a3 = (ma)[3] ? upk16(ev[1], 1) * i2 : 0.f;                    \
        const float a4 = (mb)[0] ? upk16(ev[2], 0) * i2 : 0.f;                    \
        const float a5 = (mb)[1] ? upk16(ev[2], 1) * i2 : 0.f;                    \
        const float a6 = (mb)[2] ? upk16(ev[3], 0) * i2 : 0.f;                    \
        const float a7 = (mb)[3] ? upk16(ev[3], 1) * i2 : 0.f;                    \
        f32x4 av0 = {a0, a1, a2, a3};                                             \
        f32x4 av1 = {a4, a5, a6, a7};                                             \
        __builtin_nontemporal_store(av0, (f32x4*)(Aout + crow + (s) * 256));      \
        __builtin_nontemporal_store(av1, (f32x4*)(Aout + crow + (s) * 256 + 4));  \
        u32x4 pb;                                                                 \
        pb[0] = f2bf_u(a0) | (f2bf_u(a1) << 16);                                  \
        pb[1] = f2bf_u(a2) | (f2bf_u(a3) << 16);                                  \
        pb[2] = f2bf_u(a4) | (f2bf_u(a5) << 16);                                  \
        pb[3] = f2bf_u(a6) | (f2bf_u(a7) << 16);                                  \
        *(u32x4*)ep = pb;                                                         \
    }

    {
        u32x4 ma = __builtin_nontemporal_load((const u32x4*)(Mk + crow));
        u32x4 mb = __builtin_nontemporal_load((const u32x4*)(Mk + crow + 4));
        C_FINISH(0, ma, mb);
    }
    __syncthreads();

    for (int s = 0; s < 8; ++s) {
        u32x4 na, nb;
        if (s < 7) {
            na = __builtin_nontemporal_load((const u32x4*)(Mk + crow + (s + 1) * 256));
            nb = __builtin_nontemporal_load((const u32x4*)(Mk + crow + (s + 1) * 256 + 4));
        }
        // PV on stripe s (reads repacked bf16, disjoint from stripe s+1 writes)
        #pragma unroll
        for (int c = 0; c < 4; ++c) {
            const int k0 = s * 256 + par * 128 + c * 32;
            short8 af = *(const short8*)&e_lds[m16][(k0 + koff) ^ xm];
            short8 vf = *(const short8*)(vrow + k0 + koff);
            acc = __builtin_amdgcn_mfma_f32_16x16x32_bf16(af, vf, acc, 0, 0, 0);
        }
        if (s < 7) C_FINISH(s + 1, na, nb);
        __syncthreads();
    }

    // ---- combine k-parities, write y ----
    if (par == 1) {
        #pragma unroll
        for (int r = 0; r < 4; ++r) yp[g][kq * 4 + r][m16] = acc[r];
    }
    __syncthreads();
    if (par == 0) {
        #pragma unroll
        for (int r = 0; r < 4; ++r) {
            const float yv = acc[r] + yp[g][kq * 4 + r][m16];
            __builtin_nontemporal_store(yv,
                Yout + ((size_t)b * SQ + q0 + kq * 4 + r) * DK + g * 16 + m16);
        }
    }
    #undef C_FINISH
}

extern "C" void kernel_launch(void* const* d_in, const int* in_sizes, int n_in,
                              void* d_out, int out_size, void* d_ws, size_t ws_size,
                              hipStream_t stream) {
    const float*    Q  = (const float*)d_in[0];
    const float*    K  = (const float*)d_in[1];
    const float*    V  = (const float*)d_in[2];
    const unsigned* Mk = (const unsigned*)d_in[3];
    float* Yout = (float*)d_out;
    float* Aout = (float*)d_out + (size_t)NB * SQ * DK;

    const size_t NEL = (size_t)NB * SQ * DK;
    unsigned short* Khi = (unsigned short*)d_ws;
    unsigned short* Klo = Khi + NEL;
    unsigned short* Vt  = Klo + NEL;

    prep_kernel<<<dim3(NB * (SQ / 64)), dim3(256), 0, stream>>>(K, V, Khi, Klo, Vt);
    sdpa_main<<<dim3(NB * (SQ / TQ)), dim3(NTHREADS), 0, stream>>>(
        Q, Khi, Klo, Vt, Mk, Yout, Aout);
}